// Round 7
// baseline (780.562 us; speedup 1.0000x reference)
//
#include <hip/hip_runtime.h>
#include <hip/hip_bf16.h>
#include <math.h>

// Problem constants (fixed by the reference)
#define B_    2
#define N_    120000
#define S_    40000
#define M_    30000
#define V_    100000
#define H_    256
#define WD_   1024
#define HID_  128
#define NSC_  4
#define NCLS_ 20
#define BM_   60000    // B*M rows of the image branch
#define BS_   80000    // B*S sample rows
#define BN_   240000   // B*N point rows

typedef __attribute__((ext_vector_type(8))) short bfrag8;   // 8 bf16 MFMA A/B frag
typedef __attribute__((ext_vector_type(4))) float facc4;    // 4 f32 MFMA C/D frag
typedef __attribute__((ext_vector_type(4))) unsigned short usvec4;

__device__ __forceinline__ unsigned short f2bf(float f){
  unsigned u = __builtin_bit_cast(unsigned, f);
  u += 0x7fffu + ((u >> 16) & 1u);          // round-to-nearest-even
  return (unsigned short)(u >> 16);
}
__device__ __forceinline__ float bf2f(unsigned short s){
  return __builtin_bit_cast(float, ((unsigned)s) << 16);
}

// Stage one 64-row n-half of a [.][nstride-byte] bf16 weight matrix into a
// 16KB LDS buffer (row stride 256B, XOR-swizzled).
__device__ __forceinline__ void stageW(char* wbuf, const char* src, int nstride, int tid){
  #pragma unroll
  for (int c0 = 0; c0 < 4; c0++){
    int c = c0 * 256 + tid;
    int nloc = c >> 4, off = (c & 15) << 4;
    *(bfrag8*)(wbuf + (((nloc << 8) + off) ^ ((nloc & 7) << 4))) =
        *(const bfrag8*)(src + (size_t)nloc * nstride + off);
  }
}

// One n-half MFMA quad: acc4[ctl] covers cols h*64 + ctl*16 + rl.
__device__ __forceinline__ void mfmaHalf(facc4* acc4, const bfrag8* afr,
                                         const char* wbuf, int rl, int kg){
  #pragma unroll
  for (int kc = 0; kc < 4; kc++){
    int k2 = (kc * 32 + kg * 8) << 1;
    #pragma unroll
    for (int ctl = 0; ctl < 4; ctl++){
      int nloc = ctl * 16 + rl;
      bfrag8 b = *(const bfrag8*)(wbuf + (((nloc << 8) + k2) ^ ((nloc & 7) << 4)));
      acc4[ctl] = __builtin_amdgcn_mfma_f32_16x16x32_bf16(afr[kc], b, acc4[ctl], 0, 0, 0);
    }
  }
}

// ---------------------------------------------------------------------------
// Front kernel: three independent jobs in disjoint block ranges (no LDS).
//   [0, 938)       winner scatters (last-wins == max index)
//   [938, 2228)    weight pre-transpose to bf16 [n][k]
//   [2228, 5978)   img gather: 2 rows x 4 ch per thread (8 chains ILP)
__global__ __launch_bounds__(256) void k_front(
    const float* __restrict__ img, const int* __restrict__ ptsimg,
    unsigned short* __restrict__ iap,
    const int* __restrict__ p2i, const int* __restrict__ si,
    const int* __restrict__ ci,
    int* __restrict__ win_p, int* __restrict__ win_s, int* __restrict__ win_c,
    const float* __restrict__ lW, const float* __restrict__ f1W,
    const float* __restrict__ f2W, const float* __restrict__ c1W,
    const float* __restrict__ c2W,
    unsigned short* __restrict__ lwT, unsigned short* __restrict__ f1T,
    unsigned short* __restrict__ f2T, unsigned short* __restrict__ c1T,
    unsigned short* __restrict__ c2T){
  int bid = blockIdx.x;
  if (bid < 938){                                // ---- winner scatters ----
    int t = bid * 256 + threadIdx.x;
    if (t < BM_) atomicMax(&win_p[(t / M_) * N_ + p2i[t]], t);
    if (t < BS_) atomicMax(&win_s[(t / S_) * N_ + si[t]], t);
    if (t < BN_) atomicMax(&win_c[ci[t]], t);
    return;
  }
  if (bid < 2228){                               // ---- weight prep ----
    int t = (bid - 938) * 256 + threadIdx.x;     // 330240 exact
    if (t < 65536){                              // leaner: 4 x [128][128]
      int i = t >> 14, r = t & 16383, n = r >> 7, k = r & 127;
      lwT[i * 16384 + n * 128 + k] = f2bf(lW[i * 16384 + k * 128 + n]);
    } else if (t < 196608){                      // fcs1: 4 x [128][256]
      int e = t - 65536;
      int i = e >> 15, r = e & 32767, n = r >> 8, k = r & 255;
      f1T[i * 32768 + n * 256 + k] = f2bf(f1W[i * 32768 + k * 128 + n]);
    } else if (t < 262144){                      // fcs2: 4 x [128][128]
      int e = t - 196608;
      int i = e >> 14, r = e & 16383, n = r >> 7, k = r & 127;
      f2T[i * 16384 + n * 128 + k] = f2bf(f2W[i * 16384 + k * 128 + n]);
    } else if (t < 327680){                      // cls_W1: [128][512]
      int e = t - 262144;
      int n = e >> 9, k = e & 511;
      c1T[n * 512 + k] = f2bf(c1W[k * 128 + n]);
    } else if (t < 330240){                      // cls_W2: [20][128]
      int e = t - 327680;
      int n = e >> 7, k = e & 127;
      c2T[n * 128 + k] = f2bf(c2W[k * NCLS_ + n]);
    }
    return;
  }
  {                                              // ---- img gather ----
    int t = (bid - 2228) * 256 + threadIdx.x;    // t = r0*32 + g, 3750 blocks
    int r0 = t >> 5, h4 = (t & 31) * 4;
    const size_t st = (size_t)H_ * WD_;
    #pragma unroll
    for (int half = 0; half < 2; half++){
      int row = r0 + half * 30000;               // b == half
      int r = ptsimg[row * 2 + 0];
      int c = ptsimg[row * 2 + 1];
      const float* base = img + (((size_t)half * HID_ + h4) * H_ + r) * WD_ + c;
      float v0 = base[0], v1 = base[st], v2 = base[2 * st], v3 = base[3 * st];
      usvec4 o = {f2bf(v0), f2bf(v1), f2bf(v2), f2bf(v3)};
      *(usvec4*)(iap + (size_t)row * HID_ + h4) = o;
    }
    return;
  }
}

// ---------------------------------------------------------------------------
// output_3d stream, 4 j per thread (20 independent gather chains for latency
// hiding). Zero LDS, full occupancy. NT stores (pure output stream).
__global__ __launch_bounds__(256) void k_o3d(const float* __restrict__ samp,
    const int* __restrict__ win_s, const int* __restrict__ win_p,
    const unsigned short* __restrict__ iap, float* __restrict__ o3d){
  int t = blockIdx.x * 256 + threadIdx.x;       // 7500 blocks
  int jg = t >> 5, q = t & 31;
  int j0 = jg << 2;
  int sjv[4], pjv[4];
  #pragma unroll
  for (int jj = 0; jj < 4; jj++){ sjv[jj] = win_s[j0 + jj]; pjv[jj] = win_p[j0 + jj]; }
  facc4 iv[4];
  #pragma unroll
  for (int jj = 0; jj < 4; jj++){
    facc4 v = {0.f, 0.f, 0.f, 0.f};
    if (pjv[jj] >= 0){
      usvec4 u = *(const usvec4*)(iap + (size_t)pjv[jj] * HID_ + q * 4);
      v.x = bf2f(u.x); v.y = bf2f(u.y); v.z = bf2f(u.z); v.w = bf2f(u.w);
    }
    iv[jj] = v;
  }
  #pragma unroll
  for (int i = 0; i < NSC_; i++){
    #pragma unroll
    for (int jj = 0; jj < 4; jj++){
      facc4 v = iv[jj];
      if (sjv[jj] >= 0)
        v += *(const facc4*)(samp + ((size_t)i * BS_ + sjv[jj]) * HID_ + q * 4);
      __builtin_nontemporal_store(v,
          (facc4*)(o3d + (size_t)(j0 + jj) * (NSC_ * HID_) + i * HID_ + q * 4));
    }
  }
}

// ---------------------------------------------------------------------------
// Fully fused per-row pipeline: for each 64-row tile, loop scales i=0..3
// {leaner -> fcs1 -> fcs2+gate -> cls1-chunk accumulate}, then classifier
// epilogue. seg never materialized. LDS 32KB = 16KB weight n-half buffer +
// 16KB act buffer -> 5 blocks/CU; all 938 blocks co-resident.
__global__ __launch_bounds__(256, 5) void k_fused(
    const float* __restrict__ samp, const unsigned short* __restrict__ iap,
    const int* __restrict__ win_p, const int* __restrict__ win_s,
    const int* __restrict__ win_c, const int* __restrict__ p2i,
    const int* __restrict__ ci, const float* __restrict__ imgf,
    const unsigned short* __restrict__ lwT, const float* __restrict__ lb,
    const unsigned short* __restrict__ f1T, const float* __restrict__ f1b,
    const unsigned short* __restrict__ f2T, const float* __restrict__ f2b,
    const unsigned short* __restrict__ c1T, const float* __restrict__ c1b,
    const unsigned short* __restrict__ c2T, const float* __restrict__ c2b,
    float* __restrict__ logits){
  __shared__ char lds[32768];
  char* wbuf = lds;
  char* actL = lds + 16384;
  const int tid = threadIdx.x;
  const int lane = tid & 63, wv = tid >> 6;
  const int rl = lane & 15, kg = lane >> 4;
  const int rowBase = blockIdx.x * 64 + wv * 16;
  const int row = rowBase + rl;
  const bool rv = row < BM_;
  const int lr = wv * 16 + rl;

  // chase g once per block-row; load iap row frags once (reused by 4 scales)
  int sj = -1, pj = -1;
  if (rv){
    int b = row >= M_;
    int g = win_c[ci[b * N_ + p2i[row]]];
    sj = win_s[g]; pj = win_p[g];
  }
  usvec4 ppv[8];
  #pragma unroll
  for (int e = 0; e < 8; e++) ppv[e] = (usvec4){0, 0, 0, 0};
  if (pj >= 0){
    const unsigned short* pp = iap + (size_t)pj * HID_;
    #pragma unroll
    for (int kc = 0; kc < 4; kc++){
      int k0 = kc * 32 + kg * 8;
      ppv[2 * kc]     = *(const usvec4*)(pp + k0);
      ppv[2 * kc + 1] = *(const usvec4*)(pp + k0 + 4);
    }
  }

  facc4 accC[8];                                 // persistent cls1 accumulator
  #pragma unroll
  for (int a = 0; a < 8; a++) accC[a] = (facc4){0.f, 0.f, 0.f, 0.f};

  #pragma unroll 1
  for (int i = 0; i < NSC_; i++){
    // ---- A-frags: leaner input = samp_i[sj] + iap[pj] ----
    bfrag8 afrL[4];
    {
      const float* sp = samp + ((size_t)i * BS_ + (sj < 0 ? 0 : sj)) * HID_;
      #pragma unroll
      for (int kc = 0; kc < 4; kc++){
        int k0 = kc * 32 + kg * 8;
        facc4 s0 = {0,0,0,0}, s1 = {0,0,0,0};
        if (sj >= 0){ s0 = *(const facc4*)(sp + k0); s1 = *(const facc4*)(sp + k0 + 4); }
        usvec4 u0 = ppv[2 * kc], u1 = ppv[2 * kc + 1];
        bfrag8 a;
        a[0] = (short)f2bf(s0.x + bf2f(u0.x)); a[1] = (short)f2bf(s0.y + bf2f(u0.y));
        a[2] = (short)f2bf(s0.z + bf2f(u0.z)); a[3] = (short)f2bf(s0.w + bf2f(u0.w));
        a[4] = (short)f2bf(s1.x + bf2f(u1.x)); a[5] = (short)f2bf(s1.y + bf2f(u1.y));
        a[6] = (short)f2bf(s1.z + bf2f(u1.z)); a[7] = (short)f2bf(s1.w + bf2f(u1.w));
        afrL[kc] = a;
      }
    }
    // imgf A-frags (issued early; consumed in fcs1)
    bfrag8 afrI[4];
    {
      const float* a1 = imgf + ((size_t)i * BM_ + (rv ? row : 0)) * HID_;
      #pragma unroll
      for (int kc = 0; kc < 4; kc++){
        int k0 = kc * 32 + kg * 8;
        facc4 s0 = {0,0,0,0}, s1 = {0,0,0,0};
        if (rv){ s0 = *(const facc4*)(a1 + k0); s1 = *(const facc4*)(a1 + k0 + 4); }
        bfrag8 a;
        a[0]=(short)f2bf(s0.x); a[1]=(short)f2bf(s0.y); a[2]=(short)f2bf(s0.z); a[3]=(short)f2bf(s0.w);
        a[4]=(short)f2bf(s1.x); a[5]=(short)f2bf(s1.y); a[6]=(short)f2bf(s1.z); a[7]=(short)f2bf(s1.w);
        afrI[kc] = a;
      }
    }

    // ---- leaner (two n-halves) ----
    facc4 accL[8];
    #pragma unroll
    for (int a = 0; a < 8; a++) accL[a] = (facc4){0.f, 0.f, 0.f, 0.f};
    #pragma unroll
    for (int h = 0; h < 2; h++){
      stageW(wbuf, (const char*)(lwT + (size_t)i * 16384) + (size_t)h * 64 * 256, 256, tid);
      __syncthreads();
      mfmaHalf(&accL[h * 4], afrL, wbuf, rl, kg);
      __syncthreads();
    }
    // fl = relu(accL + lb) -> act LDS (bf16, A-layout source)
    {
      const float* bias = lb + i * HID_;
      #pragma unroll
      for (int a = 0; a < 8; a++){
        int col = (a >> 2) * 64 + (a & 3) * 16 + rl;
        float bv = bias[col];
        #pragma unroll
        for (int r = 0; r < 4; r++){
          int ar = wv * 16 + kg * 4 + r;
          float v = accL[a][r] + bv; v = v > 0.f ? v : 0.f;
          int byte = ar * 256 + col * 2;
          *(unsigned short*)(actL + (byte ^ ((ar & 7) << 4))) = f2bf(v);
        }
      }
    }
    // ---- fcs1: K-half 0 (imgf) then K-half 1 (fl), each in two n-halves ----
    facc4 accF[8];
    #pragma unroll
    for (int a = 0; a < 8; a++) accF[a] = (facc4){0.f, 0.f, 0.f, 0.f};
    #pragma unroll
    for (int h = 0; h < 2; h++){
      stageW(wbuf, (const char*)(f1T + (size_t)i * 32768) + (size_t)h * 64 * 512, 512, tid);
      __syncthreads();                           // also publishes fl writes
      mfmaHalf(&accF[h * 4], afrI, wbuf, rl, kg);
      __syncthreads();
    }
    bfrag8 afrF[4];
    #pragma unroll
    for (int kc = 0; kc < 4; kc++){
      int byteA = lr * 256 + ((kc * 32 + kg * 8) << 1);
      afrF[kc] = *(const bfrag8*)(actL + (byteA ^ ((lr & 7) << 4)));
    }
    #pragma unroll
    for (int h = 0; h < 2; h++){
      stageW(wbuf, (const char*)(f1T + (size_t)i * 32768) + (size_t)h * 64 * 512 + 256, 512, tid);
      __syncthreads();
      mfmaHalf(&accF[h * 4], afrF, wbuf, rl, kg);
      __syncthreads();
    }
    // fc = accF + b1 (keep f32); also -> act LDS as bf16 for fcs2 A
    {
      const float* bias = f1b + i * HID_;
      #pragma unroll
      for (int a = 0; a < 8; a++){
        int col = (a >> 2) * 64 + (a & 3) * 16 + rl;
        float bv = bias[col];
        #pragma unroll
        for (int r = 0; r < 4; r++){
          int ar = wv * 16 + kg * 4 + r;
          float v = accF[a][r] + bv;
          accF[a][r] = v;
          int byte = ar * 256 + col * 2;
          *(unsigned short*)(actL + (byte ^ ((ar & 7) << 4))) = f2bf(v);
        }
      }
    }
    // ---- fcs2 (two n-halves) ----
    facc4 accT[8];
    #pragma unroll
    for (int a = 0; a < 8; a++) accT[a] = (facc4){0.f, 0.f, 0.f, 0.f};
    bfrag8 afrC[4];
    #pragma unroll
    for (int h = 0; h < 2; h++){
      stageW(wbuf, (const char*)(f2T + (size_t)i * 16384) + (size_t)h * 64 * 256, 256, tid);
      __syncthreads();                           // publishes fc writes (h==0)
      if (h == 0){
        #pragma unroll
        for (int kc = 0; kc < 4; kc++){
          int byteA = lr * 256 + ((kc * 32 + kg * 8) << 1);
          afrC[kc] = *(const bfrag8*)(actL + (byteA ^ ((lr & 7) << 4)));
        }
      }
      mfmaHalf(&accT[h * 4], afrC, wbuf, rl, kg);
      __syncthreads();
    }
    // gate: fuse = relu(fc * sigmoid(accT + b2)) -> act LDS
    {
      const float* bias2 = f2b + i * HID_;
      #pragma unroll
      for (int a = 0; a < 8; a++){
        int col = (a >> 2) * 64 + (a & 3) * 16 + rl;
        float bv2 = bias2[col];
        #pragma unroll
        for (int r = 0; r < 4; r++){
          int ar = wv * 16 + kg * 4 + r;
          float tv = accT[a][r] + bv2;
          float fw = 1.f / (1.f + expf(-tv));
          float u = accF[a][r] * fw;
          u = u > 0.f ? u : 0.f;
          int byte = ar * 256 + col * 2;
          *(unsigned short*)(actL + (byte ^ ((ar & 7) << 4))) = f2bf(u);
        }
      }
    }
    __syncthreads();                             // fuse published
    // ---- cls1 chunk i: accC += fuse @ W1[i*128:(i+1)*128, :] ----
    bfrag8 afrU[4];
    #pragma unroll
    for (int kc = 0; kc < 4; kc++){
      int byteA = lr * 256 + ((kc * 32 + kg * 8) << 1);
      afrU[kc] = *(const bfrag8*)(actL + (byteA ^ ((lr & 7) << 4)));
    }
    #pragma unroll
    for (int h = 0; h < 2; h++){
      stageW(wbuf, (const char*)c1T + (size_t)h * 64 * 1024 + i * 256, 1024, tid);
      __syncthreads();
      mfmaHalf(&accC[h * 4], afrU, wbuf, rl, kg);
      __syncthreads();
    }
  }

  // ---- classifier epilogue: hid = relu(accC + c1b) -> act; W2 dot ----
  #pragma unroll
  for (int a = 0; a < 8; a++){
    int col = (a >> 2) * 64 + (a & 3) * 16 + rl;
    float bv = c1b[col];
    #pragma unroll
    for (int r = 0; r < 4; r++){
      int ar = wv * 16 + kg * 4 + r;
      float v = accC[a][r] + bv; v = v > 0.f ? v : 0.f;
      int byte = ar * 256 + col * 2;
      *(unsigned short*)(actL + (byte ^ ((ar & 7) << 4))) = f2bf(v);
    }
  }
  for (int c = tid; c < 320; c += 256)
    *(bfrag8*)(wbuf + (c << 4)) = *(const bfrag8*)((const char*)c2T + (c << 4));
  __syncthreads();
  {
    int lrd = tid >> 2, n0 = (tid & 3) * 5;
    int orow = blockIdx.x * 64 + lrd;
    if (orow < BM_){
      float accD[5];
      #pragma unroll
      for (int q = 0; q < 5; q++) accD[q] = c2b[n0 + q];
      #pragma unroll
      for (int k8 = 0; k8 < 16; k8++){
        int byteA = lrd * 256 + (k8 << 4);
        bfrag8 hv = *(const bfrag8*)(actL + (byteA ^ ((lrd & 7) << 4)));
        #pragma unroll
        for (int q = 0; q < 5; q++){
          bfrag8 w8 = *(const bfrag8*)(wbuf + (n0 + q) * 256 + (k8 << 4));
          #pragma unroll
          for (int e = 0; e < 8; e++)
            accD[q] += bf2f((unsigned short)hv[e]) * bf2f((unsigned short)w8[e]);
        }
      }
      #pragma unroll
      for (int q = 0; q < 5; q++)
        logits[(size_t)orow * NCLS_ + n0 + q] = accD[q];
    }
  }
}

// ---------------------------------------------------------------------------
extern "C" void kernel_launch(void* const* d_in, const int* in_sizes, int n_in,
                              void* d_out, int out_size, void* d_ws, size_t ws_size,
                              hipStream_t stream){
  const float* samp = (const float*)d_in[1];   // pts_sample_feat (pts_feat_layers is dead)
  const float* img  = (const float*)d_in[2];
  const float* imgf = (const float*)d_in[3];
  const float* lW   = (const float*)d_in[4];
  const float* lb   = (const float*)d_in[5];
  const float* f1W  = (const float*)d_in[6];
  const float* f1b  = (const float*)d_in[7];
  const float* f2W  = (const float*)d_in[8];
  const float* f2b  = (const float*)d_in[9];
  const float* c1W  = (const float*)d_in[10];
  const float* c1b  = (const float*)d_in[11];
  const float* c2W  = (const float*)d_in[12];
  const float* c2b  = (const float*)d_in[13];
  const int* ptsimg = (const int*)d_in[14];
  const int* p2i    = (const int*)d_in[15];
  const int* si     = (const int*)d_in[16];
  const int* ci     = (const int*)d_in[17];

  char* ws = (char*)d_ws;
  int*   win_p = (int*)(ws + 0);                       //   960,000 B
  int*   win_s = (int*)(ws + 960000);                  //   960,000 B
  int*   win_c = (int*)(ws + 1920000);                 //   400,000 B
  unsigned short* iap = (unsigned short*)(ws + 2320128);    // 15,360,000 B
  unsigned short* lwT = (unsigned short*)(ws + 17680384);   // 131,072 B
  unsigned short* f1T = lwT + 65536;                        // 262,144 B
  unsigned short* f2T = f1T + 131072;                       // 131,072 B
  unsigned short* c1T = f2T + 65536;                        // 131,072 B
  unsigned short* c2T = c1T + 65536;                        //   5,120 B

  float* logits = (float*)d_out;
  float* o3d    = (float*)d_out + (size_t)BM_ * NCLS_;

  (void)hipMemsetAsync(ws, 0xFF, 2320000, stream);     // win_* = -1
  k_front<<<5978, 256, 0, stream>>>(img, ptsimg, iap, p2i, si, ci,
                                    win_p, win_s, win_c,
                                    lW, f1W, f2W, c1W, c2W,
                                    lwT, f1T, f2T, c1T, c2T);
  k_o3d  <<<7500, 256, 0, stream>>>(samp, win_s, win_p, iap, o3d);
  k_fused<<<938,  256, 0, stream>>>(samp, iap, win_p, win_s, win_c, p2i, ci,
                                    imgf, lwT, lb, f1T, f1b, f2T, f2b,
                                    c1T, c1b, c2T, c2b, logits);
}

// Round 8
// 610.377 us; speedup vs baseline: 1.2788x; 1.2788x over previous
//
#include <hip/hip_runtime.h>
#include <hip/hip_bf16.h>
#include <math.h>

// Problem constants (fixed by the reference)
#define B_    2
#define N_    120000
#define S_    40000
#define M_    30000
#define V_    100000
#define H_    256
#define WD_   1024
#define HID_  128
#define NSC_  4
#define NCLS_ 20
#define BM_   60000    // B*M rows of the image branch
#define BS_   80000    // B*S sample rows
#define BN_   240000   // B*N point rows

#define FUSED_BLKS 938           // ceil(60000/64)
#define O3D_BLKS   7500          // 240000 j x 32 lanes / 256 / 4 j-per-thread

typedef __attribute__((ext_vector_type(8))) short bfrag8;   // 8 bf16 MFMA A/B frag
typedef __attribute__((ext_vector_type(4))) float facc4;    // 4 f32 MFMA C/D frag
typedef __attribute__((ext_vector_type(4))) unsigned short usvec4;

__device__ __forceinline__ unsigned short f2bf(float f){
  unsigned u = __builtin_bit_cast(unsigned, f);
  u += 0x7fffu + ((u >> 16) & 1u);          // round-to-nearest-even
  return (unsigned short)(u >> 16);
}
__device__ __forceinline__ float bf2f(unsigned short s){
  return __builtin_bit_cast(float, ((unsigned)s) << 16);
}

// Stage one 64-row n-half of a [.][nstride-byte] bf16 weight matrix into a
// 16KB LDS buffer (row stride 256B, XOR-swizzled).
__device__ __forceinline__ void stageW(char* wbuf, const char* src, int nstride, int tid){
  #pragma unroll
  for (int c0 = 0; c0 < 4; c0++){
    int c = c0 * 256 + tid;
    int nloc = c >> 4, off = (c & 15) << 4;
    *(bfrag8*)(wbuf + (((nloc << 8) + off) ^ ((nloc & 7) << 4))) =
        *(const bfrag8*)(src + (size_t)nloc * nstride + off);
  }
}

// One n-half MFMA quad: acc4[ctl] covers cols h*64 + ctl*16 + rl.
__device__ __forceinline__ void mfmaHalf(facc4* acc4, const bfrag8* afr,
                                         const char* wbuf, int rl, int kg){
  #pragma unroll
  for (int kc = 0; kc < 4; kc++){
    int k2 = (kc * 32 + kg * 8) << 1;
    #pragma unroll
    for (int ctl = 0; ctl < 4; ctl++){
      int nloc = ctl * 16 + rl;
      bfrag8 b = *(const bfrag8*)(wbuf + (((nloc << 8) + k2) ^ ((nloc & 7) << 4)));
      acc4[ctl] = __builtin_amdgcn_mfma_f32_16x16x32_bf16(afr[kc], b, acc4[ctl], 0, 0, 0);
    }
  }
}

// ---------------------------------------------------------------------------
// Front kernel: three independent jobs in disjoint block ranges (no LDS).
//   [0, 938)       winner scatters (last-wins == max index)
//   [938, 2228)    weight pre-transpose to bf16 [n][k]
//   [2228, 5978)   img gather: 2 rows x 4 ch per thread (8 chains ILP)
__global__ __launch_bounds__(256) void k_front(
    const float* __restrict__ img, const int* __restrict__ ptsimg,
    unsigned short* __restrict__ iap,
    const int* __restrict__ p2i, const int* __restrict__ si,
    const int* __restrict__ ci,
    int* __restrict__ win_p, int* __restrict__ win_s, int* __restrict__ win_c,
    const float* __restrict__ lW, const float* __restrict__ f1W,
    const float* __restrict__ f2W, const float* __restrict__ c1W,
    const float* __restrict__ c2W,
    unsigned short* __restrict__ lwT, unsigned short* __restrict__ f1T,
    unsigned short* __restrict__ f2T, unsigned short* __restrict__ c1T,
    unsigned short* __restrict__ c2T){
  int bid = blockIdx.x;
  if (bid < 938){                                // ---- winner scatters ----
    int t = bid * 256 + threadIdx.x;
    if (t < BM_) atomicMax(&win_p[(t / M_) * N_ + p2i[t]], t);
    if (t < BS_) atomicMax(&win_s[(t / S_) * N_ + si[t]], t);
    if (t < BN_) atomicMax(&win_c[ci[t]], t);
    return;
  }
  if (bid < 2228){                               // ---- weight prep ----
    int t = (bid - 938) * 256 + threadIdx.x;     // 330240 exact
    if (t < 65536){                              // leaner: 4 x [128][128]
      int i = t >> 14, r = t & 16383, n = r >> 7, k = r & 127;
      lwT[i * 16384 + n * 128 + k] = f2bf(lW[i * 16384 + k * 128 + n]);
    } else if (t < 196608){                      // fcs1: 4 x [128][256]
      int e = t - 65536;
      int i = e >> 15, r = e & 32767, n = r >> 8, k = r & 255;
      f1T[i * 32768 + n * 256 + k] = f2bf(f1W[i * 32768 + k * 128 + n]);
    } else if (t < 262144){                      // fcs2: 4 x [128][128]
      int e = t - 196608;
      int i = e >> 14, r = e & 16383, n = r >> 7, k = r & 127;
      f2T[i * 16384 + n * 128 + k] = f2bf(f2W[i * 16384 + k * 128 + n]);
    } else if (t < 327680){                      // cls_W1: [128][512]
      int e = t - 262144;
      int n = e >> 9, k = e & 511;
      c1T[n * 512 + k] = f2bf(c1W[k * 128 + n]);
    } else if (t < 330240){                      // cls_W2: [20][128]
      int e = t - 327680;
      int n = e >> 7, k = e & 127;
      c2T[n * 128 + k] = f2bf(c2W[k * NCLS_ + n]);
    }
    return;
  }
  {                                              // ---- img gather ----
    int t = (bid - 2228) * 256 + threadIdx.x;    // t = r0*32 + g, 3750 blocks
    int r0 = t >> 5, h4 = (t & 31) * 4;
    const size_t st = (size_t)H_ * WD_;
    #pragma unroll
    for (int half = 0; half < 2; half++){
      int row = r0 + half * 30000;               // b == half
      int r = ptsimg[row * 2 + 0];
      int c = ptsimg[row * 2 + 1];
      const float* base = img + (((size_t)half * HID_ + h4) * H_ + r) * WD_ + c;
      float v0 = __builtin_nontemporal_load(base);
      float v1 = __builtin_nontemporal_load(base + st);
      float v2 = __builtin_nontemporal_load(base + 2 * st);
      float v3 = __builtin_nontemporal_load(base + 3 * st);
      usvec4 o = {f2bf(v0), f2bf(v1), f2bf(v2), f2bf(v3)};
      *(usvec4*)(iap + (size_t)row * HID_ + h4) = o;
    }
    return;
  }
}

// ---------------------------------------------------------------------------
// Heavy kernel. Blocks [0, 938): fused per-row MLP+classifier pipeline
// (barrier/MFMA-laced, ~35 GB HBM need). Blocks [938, 8438): output_3d
// stream (pure BW, 20 independent gather chains/thread -> latency-robust at
// 3 blocks/CU). Launched fused-first so compute blocks occupy CUs while the
// stream backfills idle memory slots.
// LDS 32KB = 16KB weight n-half buffer + 16KB act buffer.
// __launch_bounds__(256, 3): 3 waves/EU min -> VGPR cap ~170 (NO SPILL —
// round-7's (256,5) capped at 102 and spilled 1.3 GB of scratch).
__global__ __launch_bounds__(256, 3) void k_heavy(
    const float* __restrict__ samp, const unsigned short* __restrict__ iap,
    const int* __restrict__ win_p, const int* __restrict__ win_s,
    const int* __restrict__ win_c, const int* __restrict__ p2i,
    const int* __restrict__ ci, const float* __restrict__ imgf,
    const unsigned short* __restrict__ lwT, const float* __restrict__ lb,
    const unsigned short* __restrict__ f1T, const float* __restrict__ f1b,
    const unsigned short* __restrict__ f2T, const float* __restrict__ f2b,
    const unsigned short* __restrict__ c1T, const float* __restrict__ c1b,
    const unsigned short* __restrict__ c2T, const float* __restrict__ c2b,
    float* __restrict__ logits, float* __restrict__ o3d){
  __shared__ char lds[32768];
  if (blockIdx.x >= FUSED_BLKS){
    // ---- output_3d stream: 4 j per thread ----
    int t = (blockIdx.x - FUSED_BLKS) * 256 + threadIdx.x;
    int jg = t >> 5, q = t & 31;
    int j0 = jg << 2;
    int sjv[4], pjv[4];
    #pragma unroll
    for (int jj = 0; jj < 4; jj++){ sjv[jj] = win_s[j0 + jj]; pjv[jj] = win_p[j0 + jj]; }
    facc4 iv[4];
    #pragma unroll
    for (int jj = 0; jj < 4; jj++){
      facc4 v = {0.f, 0.f, 0.f, 0.f};
      if (pjv[jj] >= 0){
        usvec4 u = *(const usvec4*)(iap + (size_t)pjv[jj] * HID_ + q * 4);
        v.x = bf2f(u.x); v.y = bf2f(u.y); v.z = bf2f(u.z); v.w = bf2f(u.w);
      }
      iv[jj] = v;
    }
    #pragma unroll
    for (int i = 0; i < NSC_; i++){
      #pragma unroll
      for (int jj = 0; jj < 4; jj++){
        facc4 v = iv[jj];
        if (sjv[jj] >= 0)
          v += *(const facc4*)(samp + ((size_t)i * BS_ + sjv[jj]) * HID_ + q * 4);
        __builtin_nontemporal_store(v,
            (facc4*)(o3d + (size_t)(j0 + jj) * (NSC_ * HID_) + i * HID_ + q * 4));
      }
    }
    return;
  }
  // ---- fused MLP + classifier over 64 rows ----
  char* wbuf = lds;
  char* actL = lds + 16384;
  const int tid = threadIdx.x;
  const int lane = tid & 63, wv = tid >> 6;
  const int rl = lane & 15, kg = lane >> 4;
  const int rowBase = blockIdx.x * 64 + wv * 16;
  const int row = rowBase + rl;
  const bool rv = row < BM_;
  const int lr = wv * 16 + rl;

  // chase g once; load iap row frags once (reused by all 4 scales)
  int sj = -1, pj = -1;
  if (rv){
    int b = row >= M_;
    int g = win_c[ci[b * N_ + p2i[row]]];
    sj = win_s[g]; pj = win_p[g];
  }
  usvec4 ppv[8];
  #pragma unroll
  for (int e = 0; e < 8; e++) ppv[e] = (usvec4){0, 0, 0, 0};
  if (pj >= 0){
    const unsigned short* pp = iap + (size_t)pj * HID_;
    #pragma unroll
    for (int kc = 0; kc < 4; kc++){
      int k0 = kc * 32 + kg * 8;
      ppv[2 * kc]     = *(const usvec4*)(pp + k0);
      ppv[2 * kc + 1] = *(const usvec4*)(pp + k0 + 4);
    }
  }

  facc4 accC[8];                                 // persistent cls1 accumulator
  #pragma unroll
  for (int a = 0; a < 8; a++) accC[a] = (facc4){0.f, 0.f, 0.f, 0.f};

  #pragma unroll 1
  for (int i = 0; i < NSC_; i++){
    // ---- A-frags: leaner input = samp_i[sj] + iap[pj] ----
    bfrag8 afrL[4];
    {
      const float* sp = samp + ((size_t)i * BS_ + (sj < 0 ? 0 : sj)) * HID_;
      #pragma unroll
      for (int kc = 0; kc < 4; kc++){
        int k0 = kc * 32 + kg * 8;
        facc4 s0 = {0,0,0,0}, s1 = {0,0,0,0};
        if (sj >= 0){ s0 = *(const facc4*)(sp + k0); s1 = *(const facc4*)(sp + k0 + 4); }
        usvec4 u0 = ppv[2 * kc], u1 = ppv[2 * kc + 1];
        bfrag8 a;
        a[0] = (short)f2bf(s0.x + bf2f(u0.x)); a[1] = (short)f2bf(s0.y + bf2f(u0.y));
        a[2] = (short)f2bf(s0.z + bf2f(u0.z)); a[3] = (short)f2bf(s0.w + bf2f(u0.w));
        a[4] = (short)f2bf(s1.x + bf2f(u1.x)); a[5] = (short)f2bf(s1.y + bf2f(u1.y));
        a[6] = (short)f2bf(s1.z + bf2f(u1.z)); a[7] = (short)f2bf(s1.w + bf2f(u1.w));
        afrL[kc] = a;
      }
    }
    // imgf A-frags (issued early; consumed in fcs1)
    bfrag8 afrI[4];
    {
      const float* a1 = imgf + ((size_t)i * BM_ + (rv ? row : 0)) * HID_;
      #pragma unroll
      for (int kc = 0; kc < 4; kc++){
        int k0 = kc * 32 + kg * 8;
        facc4 s0 = {0,0,0,0}, s1 = {0,0,0,0};
        if (rv){ s0 = *(const facc4*)(a1 + k0); s1 = *(const facc4*)(a1 + k0 + 4); }
        bfrag8 a;
        a[0]=(short)f2bf(s0.x); a[1]=(short)f2bf(s0.y); a[2]=(short)f2bf(s0.z); a[3]=(short)f2bf(s0.w);
        a[4]=(short)f2bf(s1.x); a[5]=(short)f2bf(s1.y); a[6]=(short)f2bf(s1.z); a[7]=(short)f2bf(s1.w);
        afrI[kc] = a;
      }
    }

    // ---- leaner (two n-halves) ----
    facc4 accL[8];
    #pragma unroll
    for (int a = 0; a < 8; a++) accL[a] = (facc4){0.f, 0.f, 0.f, 0.f};
    #pragma unroll
    for (int h = 0; h < 2; h++){
      stageW(wbuf, (const char*)(lwT + (size_t)i * 16384) + (size_t)h * 64 * 256, 256, tid);
      __syncthreads();
      mfmaHalf(&accL[h * 4], afrL, wbuf, rl, kg);
      __syncthreads();
    }
    // fl = relu(accL + lb) -> act LDS (bf16)
    {
      const float* bias = lb + i * HID_;
      #pragma unroll
      for (int a = 0; a < 8; a++){
        int col = (a >> 2) * 64 + (a & 3) * 16 + rl;
        float bv = bias[col];
        #pragma unroll
        for (int r = 0; r < 4; r++){
          int ar = wv * 16 + kg * 4 + r;
          float v = accL[a][r] + bv; v = v > 0.f ? v : 0.f;
          int byte = ar * 256 + col * 2;
          *(unsigned short*)(actL + (byte ^ ((ar & 7) << 4))) = f2bf(v);
        }
      }
    }
    // ---- fcs1: K-half 0 (imgf) then K-half 1 (fl), each in two n-halves ----
    facc4 accF[8];
    #pragma unroll
    for (int a = 0; a < 8; a++) accF[a] = (facc4){0.f, 0.f, 0.f, 0.f};
    #pragma unroll
    for (int h = 0; h < 2; h++){
      stageW(wbuf, (const char*)(f1T + (size_t)i * 32768) + (size_t)h * 64 * 512, 512, tid);
      __syncthreads();                           // also publishes fl writes
      mfmaHalf(&accF[h * 4], afrI, wbuf, rl, kg);
      __syncthreads();
    }
    bfrag8 afrF[4];
    #pragma unroll
    for (int kc = 0; kc < 4; kc++){
      int byteA = lr * 256 + ((kc * 32 + kg * 8) << 1);
      afrF[kc] = *(const bfrag8*)(actL + (byteA ^ ((lr & 7) << 4)));
    }
    #pragma unroll
    for (int h = 0; h < 2; h++){
      stageW(wbuf, (const char*)(f1T + (size_t)i * 32768) + (size_t)h * 64 * 512 + 256, 512, tid);
      __syncthreads();
      mfmaHalf(&accF[h * 4], afrF, wbuf, rl, kg);
      __syncthreads();
    }
    // fc = accF + b1 (keep f32); also -> act LDS as bf16 for fcs2 A
    {
      const float* bias = f1b + i * HID_;
      #pragma unroll
      for (int a = 0; a < 8; a++){
        int col = (a >> 2) * 64 + (a & 3) * 16 + rl;
        float bv = bias[col];
        #pragma unroll
        for (int r = 0; r < 4; r++){
          int ar = wv * 16 + kg * 4 + r;
          float v = accF[a][r] + bv;
          accF[a][r] = v;
          int byte = ar * 256 + col * 2;
          *(unsigned short*)(actL + (byte ^ ((ar & 7) << 4))) = f2bf(v);
        }
      }
    }
    // ---- fcs2 (two n-halves) ----
    facc4 accT[8];
    #pragma unroll
    for (int a = 0; a < 8; a++) accT[a] = (facc4){0.f, 0.f, 0.f, 0.f};
    bfrag8 afrC[4];
    #pragma unroll
    for (int h = 0; h < 2; h++){
      stageW(wbuf, (const char*)(f2T + (size_t)i * 16384) + (size_t)h * 64 * 256, 256, tid);
      __syncthreads();                           // publishes fc writes (h==0)
      if (h == 0){
        #pragma unroll
        for (int kc = 0; kc < 4; kc++){
          int byteA = lr * 256 + ((kc * 32 + kg * 8) << 1);
          afrC[kc] = *(const bfrag8*)(actL + (byteA ^ ((lr & 7) << 4)));
        }
      }
      mfmaHalf(&accT[h * 4], afrC, wbuf, rl, kg);
      __syncthreads();
    }
    // gate: fuse = relu(fc * sigmoid(accT + b2)) -> act LDS
    {
      const float* bias2 = f2b + i * HID_;
      #pragma unroll
      for (int a = 0; a < 8; a++){
        int col = (a >> 2) * 64 + (a & 3) * 16 + rl;
        float bv2 = bias2[col];
        #pragma unroll
        for (int r = 0; r < 4; r++){
          int ar = wv * 16 + kg * 4 + r;
          float tv = accT[a][r] + bv2;
          float fw = 1.f / (1.f + expf(-tv));
          float u = accF[a][r] * fw;
          u = u > 0.f ? u : 0.f;
          int byte = ar * 256 + col * 2;
          *(unsigned short*)(actL + (byte ^ ((ar & 7) << 4))) = f2bf(u);
        }
      }
    }
    __syncthreads();                             // fuse published
    // ---- cls1 chunk i: accC += fuse @ W1[i*128:(i+1)*128, :] ----
    bfrag8 afrU[4];
    #pragma unroll
    for (int kc = 0; kc < 4; kc++){
      int byteA = lr * 256 + ((kc * 32 + kg * 8) << 1);
      afrU[kc] = *(const bfrag8*)(actL + (byteA ^ ((lr & 7) << 4)));
    }
    #pragma unroll
    for (int h = 0; h < 2; h++){
      stageW(wbuf, (const char*)c1T + (size_t)h * 64 * 1024 + i * 256, 1024, tid);
      __syncthreads();
      mfmaHalf(&accC[h * 4], afrU, wbuf, rl, kg);
      __syncthreads();
    }
  }

  // ---- classifier epilogue: hid = relu(accC + c1b) -> act; W2 dot ----
  #pragma unroll
  for (int a = 0; a < 8; a++){
    int col = (a >> 2) * 64 + (a & 3) * 16 + rl;
    float bv = c1b[col];
    #pragma unroll
    for (int r = 0; r < 4; r++){
      int ar = wv * 16 + kg * 4 + r;
      float v = accC[a][r] + bv; v = v > 0.f ? v : 0.f;
      int byte = ar * 256 + col * 2;
      *(unsigned short*)(actL + (byte ^ ((ar & 7) << 4))) = f2bf(v);
    }
  }
  for (int c = tid; c < 320; c += 256)
    *(bfrag8*)(wbuf + (c << 4)) = *(const bfrag8*)((const char*)c2T + (c << 4));
  __syncthreads();
  {
    int lrd = tid >> 2, n0 = (tid & 3) * 5;
    int orow = blockIdx.x * 64 + lrd;
    if (orow < BM_){
      float accD[5];
      #pragma unroll
      for (int q = 0; q < 5; q++) accD[q] = c2b[n0 + q];
      #pragma unroll
      for (int k8 = 0; k8 < 16; k8++){
        int byteA = lrd * 256 + (k8 << 4);
        bfrag8 hv = *(const bfrag8*)(actL + (byteA ^ ((lrd & 7) << 4)));
        #pragma unroll
        for (int q = 0; q < 5; q++){
          bfrag8 w8 = *(const bfrag8*)(wbuf + (n0 + q) * 256 + (k8 << 4));
          #pragma unroll
          for (int e = 0; e < 8; e++)
            accD[q] += bf2f((unsigned short)hv[e]) * bf2f((unsigned short)w8[e]);
        }
      }
      #pragma unroll
      for (int q = 0; q < 5; q++)
        logits[(size_t)orow * NCLS_ + n0 + q] = accD[q];
    }
  }
}

// ---------------------------------------------------------------------------
extern "C" void kernel_launch(void* const* d_in, const int* in_sizes, int n_in,
                              void* d_out, int out_size, void* d_ws, size_t ws_size,
                              hipStream_t stream){
  const float* samp = (const float*)d_in[1];   // pts_sample_feat (pts_feat_layers is dead)
  const float* img  = (const float*)d_in[2];
  const float* imgf = (const float*)d_in[3];
  const float* lW   = (const float*)d_in[4];
  const float* lb   = (const float*)d_in[5];
  const float* f1W  = (const float*)d_in[6];
  const float* f1b  = (const float*)d_in[7];
  const float* f2W  = (const float*)d_in[8];
  const float* f2b  = (const float*)d_in[9];
  const float* c1W  = (const float*)d_in[10];
  const float* c1b  = (const float*)d_in[11];
  const float* c2W  = (const float*)d_in[12];
  const float* c2b  = (const float*)d_in[13];
  const int* ptsimg = (const int*)d_in[14];
  const int* p2i    = (const int*)d_in[15];
  const int* si     = (const int*)d_in[16];
  const int* ci     = (const int*)d_in[17];

  char* ws = (char*)d_ws;
  int*   win_p = (int*)(ws + 0);                       //   960,000 B
  int*   win_s = (int*)(ws + 960000);                  //   960,000 B
  int*   win_c = (int*)(ws + 1920000);                 //   400,000 B
  unsigned short* iap = (unsigned short*)(ws + 2320128);    // 15,360,000 B
  unsigned short* lwT = (unsigned short*)(ws + 17680384);   // 131,072 B
  unsigned short* f1T = lwT + 65536;                        // 262,144 B
  unsigned short* f2T = f1T + 131072;                       // 131,072 B
  unsigned short* c1T = f2T + 65536;                        // 131,072 B
  unsigned short* c2T = c1T + 65536;                        //   5,120 B

  float* logits = (float*)d_out;
  float* o3d    = (float*)d_out + (size_t)BM_ * NCLS_;

  (void)hipMemsetAsync(ws, 0xFF, 2320000, stream);     // win_* = -1
  k_front<<<5978, 256, 0, stream>>>(img, ptsimg, iap, p2i, si, ci,
                                    win_p, win_s, win_c,
                                    lW, f1W, f2W, c1W, c2W,
                                    lwT, f1T, f2T, c1T, c2T);
  k_heavy<<<FUSED_BLKS + O3D_BLKS, 256, 0, stream>>>(samp, iap,
                                    win_p, win_s, win_c, p2i, ci,
                                    imgf, lwT, lb, f1T, f1b, f2T, f2b,
                                    c1T, c1b, c2T, c2b, logits, o3d);
}

// Round 9
// 607.387 us; speedup vs baseline: 1.2851x; 1.0049x over previous
//
#include <hip/hip_runtime.h>
#include <hip/hip_bf16.h>
#include <math.h>

// Problem constants (fixed by the reference)
#define B_    2
#define N_    120000
#define S_    40000
#define M_    30000
#define V_    100000
#define H_    256
#define WD_   1024
#define HID_  128
#define NSC_  4
#define NCLS_ 20
#define BM_   60000    // B*M rows of the image branch
#define BS_   80000    // B*S sample rows
#define BN_   240000   // B*N point rows

typedef __attribute__((ext_vector_type(8))) short bfrag8;   // 8 bf16 MFMA A/B frag
typedef __attribute__((ext_vector_type(4))) float facc4;    // 4 f32 MFMA C/D frag
typedef __attribute__((ext_vector_type(4))) unsigned short usvec4;

__device__ __forceinline__ unsigned short f2bf(float f){
  unsigned u = __builtin_bit_cast(unsigned, f);
  u += 0x7fffu + ((u >> 16) & 1u);          // round-to-nearest-even
  return (unsigned short)(u >> 16);
}
__device__ __forceinline__ float bf2f(unsigned short s){
  return __builtin_bit_cast(float, ((unsigned)s) << 16);
}

// Stage one 64-row n-half of a [.][nstride-byte] bf16 weight matrix into a
// 16KB LDS buffer (row stride 256B, XOR-swizzled).
__device__ __forceinline__ void stageW(char* wbuf, const char* src, int nstride, int tid){
  #pragma unroll
  for (int c0 = 0; c0 < 4; c0++){
    int c = c0 * 256 + tid;
    int nloc = c >> 4, off = (c & 15) << 4;
    *(bfrag8*)(wbuf + (((nloc << 8) + off) ^ ((nloc & 7) << 4))) =
        *(const bfrag8*)(src + (size_t)nloc * nstride + off);
  }
}

// One n-half MFMA quad: acc4[ctl] covers cols h*64 + ctl*16 + rl.
__device__ __forceinline__ void mfmaHalf(facc4* acc4, const bfrag8* afr,
                                         const char* wbuf, int rl, int kg){
  #pragma unroll
  for (int kc = 0; kc < 4; kc++){
    int k2 = (kc * 32 + kg * 8) << 1;
    #pragma unroll
    for (int ctl = 0; ctl < 4; ctl++){
      int nloc = ctl * 16 + rl;
      bfrag8 b = *(const bfrag8*)(wbuf + (((nloc << 8) + k2) ^ ((nloc & 7) << 4)));
      acc4[ctl] = __builtin_amdgcn_mfma_f32_16x16x32_bf16(afr[kc], b, acc4[ctl], 0, 0, 0);
    }
  }
}

// ---------------------------------------------------------------------------
// Front kernel: three independent jobs in disjoint block ranges (no LDS).
//   [0, 938)       winner scatters (last-wins == max index)
//   [938, 2228)    weight pre-transpose to bf16 [n][k]
//   [2228, 5978)   img gather: 2 rows x 4 ch per thread (8 chains ILP)
__global__ __launch_bounds__(256) void k_front(
    const float* __restrict__ img, const int* __restrict__ ptsimg,
    unsigned short* __restrict__ iap,
    const int* __restrict__ p2i, const int* __restrict__ si,
    const int* __restrict__ ci,
    int* __restrict__ win_p, int* __restrict__ win_s, int* __restrict__ win_c,
    const float* __restrict__ lW, const float* __restrict__ f1W,
    const float* __restrict__ f2W, const float* __restrict__ c1W,
    const float* __restrict__ c2W,
    unsigned short* __restrict__ lwT, unsigned short* __restrict__ f1T,
    unsigned short* __restrict__ f2T, unsigned short* __restrict__ c1T,
    unsigned short* __restrict__ c2T){
  int bid = blockIdx.x;
  if (bid < 938){                                // ---- winner scatters ----
    int t = bid * 256 + threadIdx.x;
    if (t < BM_) atomicMax(&win_p[(t / M_) * N_ + p2i[t]], t);
    if (t < BS_) atomicMax(&win_s[(t / S_) * N_ + si[t]], t);
    if (t < BN_) atomicMax(&win_c[ci[t]], t);
    return;
  }
  if (bid < 2228){                               // ---- weight prep ----
    int t = (bid - 938) * 256 + threadIdx.x;     // 330240 exact
    if (t < 65536){                              // leaner: 4 x [128][128]
      int i = t >> 14, r = t & 16383, n = r >> 7, k = r & 127;
      lwT[i * 16384 + n * 128 + k] = f2bf(lW[i * 16384 + k * 128 + n]);
    } else if (t < 196608){                      // fcs1: 4 x [128][256]
      int e = t - 65536;
      int i = e >> 15, r = e & 32767, n = r >> 8, k = r & 255;
      f1T[i * 32768 + n * 256 + k] = f2bf(f1W[i * 32768 + k * 128 + n]);
    } else if (t < 262144){                      // fcs2: 4 x [128][128]
      int e = t - 196608;
      int i = e >> 14, r = e & 16383, n = r >> 7, k = r & 127;
      f2T[i * 16384 + n * 128 + k] = f2bf(f2W[i * 16384 + k * 128 + n]);
    } else if (t < 327680){                      // cls_W1: [128][512]
      int e = t - 262144;
      int n = e >> 9, k = e & 511;
      c1T[n * 512 + k] = f2bf(c1W[k * 128 + n]);
    } else if (t < 330240){                      // cls_W2: [20][128]
      int e = t - 327680;
      int n = e >> 7, k = e & 127;
      c2T[n * 128 + k] = f2bf(c2W[k * NCLS_ + n]);
    }
    return;
  }
  {                                              // ---- img gather ----
    int t = (bid - 2228) * 256 + threadIdx.x;    // t = r0*32 + g, 3750 blocks
    int r0 = t >> 5, h4 = (t & 31) * 4;
    const size_t st = (size_t)H_ * WD_;
    #pragma unroll
    for (int half = 0; half < 2; half++){
      int row = r0 + half * 30000;               // b == half
      int r = ptsimg[row * 2 + 0];
      int c = ptsimg[row * 2 + 1];
      const float* base = img + (((size_t)half * HID_ + h4) * H_ + r) * WD_ + c;
      float v0 = __builtin_nontemporal_load(base);
      float v1 = __builtin_nontemporal_load(base + st);
      float v2 = __builtin_nontemporal_load(base + 2 * st);
      float v3 = __builtin_nontemporal_load(base + 3 * st);
      usvec4 o = {f2bf(v0), f2bf(v1), f2bf(v2), f2bf(v3)};
      *(usvec4*)(iap + (size_t)row * HID_ + h4) = o;
    }
    return;
  }
}

// ---------------------------------------------------------------------------
// output_3d stream — STANDALONE at full occupancy (zero LDS, no bounds).
// 4 j per thread (20 gather chains) and BRANCH-FREE clamped loads: index is
// clamped to 0 and the value selected, so all loads issue unconditionally
// (wasted ones hit the cached row-0 line). NT stores (pure output stream).
__global__ __launch_bounds__(256) void k_o3d(const float* __restrict__ samp,
    const int* __restrict__ win_s, const int* __restrict__ win_p,
    const unsigned short* __restrict__ iap, float* __restrict__ o3d){
  const facc4 zero = {0.f, 0.f, 0.f, 0.f};
  int t = blockIdx.x * 256 + threadIdx.x;       // 7500 blocks
  int jg = t >> 5, q = t & 31;
  int j0 = jg << 2;
  int sjv[4], pjv[4];
  #pragma unroll
  for (int jj = 0; jj < 4; jj++){ sjv[jj] = win_s[j0 + jj]; pjv[jj] = win_p[j0 + jj]; }
  facc4 iv[4];
  #pragma unroll
  for (int jj = 0; jj < 4; jj++){
    int p = pjv[jj] < 0 ? 0 : pjv[jj];
    usvec4 u = *(const usvec4*)(iap + (size_t)p * HID_ + q * 4);
    facc4 v = {bf2f(u.x), bf2f(u.y), bf2f(u.z), bf2f(u.w)};
    iv[jj] = pjv[jj] >= 0 ? v : zero;
  }
  #pragma unroll
  for (int i = 0; i < NSC_; i++){
    #pragma unroll
    for (int jj = 0; jj < 4; jj++){
      int s = sjv[jj] < 0 ? 0 : sjv[jj];
      facc4 sv = *(const facc4*)(samp + ((size_t)i * BS_ + s) * HID_ + q * 4);
      facc4 v = iv[jj] + (sjv[jj] >= 0 ? sv : zero);
      __builtin_nontemporal_store(v,
          (facc4*)(o3d + (size_t)(j0 + jj) * (NSC_ * HID_) + i * HID_ + q * 4));
    }
  }
}

// ---------------------------------------------------------------------------
// Fused per-row MLP + classifier (seg never materialized). 64 rows/block.
// LDS 32KB = 16KB weight n-half buffer + 16KB act buffer.
// __launch_bounds__(256, 3): VGPR cap ~170; measured 84 VGPR, no spill (r8).
__global__ __launch_bounds__(256, 3) void k_fused(
    const float* __restrict__ samp, const unsigned short* __restrict__ iap,
    const int* __restrict__ win_p, const int* __restrict__ win_s,
    const int* __restrict__ win_c, const int* __restrict__ p2i,
    const int* __restrict__ ci, const float* __restrict__ imgf,
    const unsigned short* __restrict__ lwT, const float* __restrict__ lb,
    const unsigned short* __restrict__ f1T, const float* __restrict__ f1b,
    const unsigned short* __restrict__ f2T, const float* __restrict__ f2b,
    const unsigned short* __restrict__ c1T, const float* __restrict__ c1b,
    const unsigned short* __restrict__ c2T, const float* __restrict__ c2b,
    float* __restrict__ logits){
  __shared__ char lds[32768];
  char* wbuf = lds;
  char* actL = lds + 16384;
  const int tid = threadIdx.x;
  const int lane = tid & 63, wv = tid >> 6;
  const int rl = lane & 15, kg = lane >> 4;
  const int rowBase = blockIdx.x * 64 + wv * 16;
  const int row = rowBase + rl;
  const bool rv = row < BM_;
  const int lr = wv * 16 + rl;

  // chase g once; load iap row frags once (reused by all 4 scales)
  int sj = -1, pj = -1;
  if (rv){
    int b = row >= M_;
    int g = win_c[ci[b * N_ + p2i[row]]];
    sj = win_s[g]; pj = win_p[g];
  }
  usvec4 ppv[8];
  #pragma unroll
  for (int e = 0; e < 8; e++) ppv[e] = (usvec4){0, 0, 0, 0};
  if (pj >= 0){
    const unsigned short* pp = iap + (size_t)pj * HID_;
    #pragma unroll
    for (int kc = 0; kc < 4; kc++){
      int k0 = kc * 32 + kg * 8;
      ppv[2 * kc]     = *(const usvec4*)(pp + k0);
      ppv[2 * kc + 1] = *(const usvec4*)(pp + k0 + 4);
    }
  }

  facc4 accC[8];                                 // persistent cls1 accumulator
  #pragma unroll
  for (int a = 0; a < 8; a++) accC[a] = (facc4){0.f, 0.f, 0.f, 0.f};

  #pragma unroll 1
  for (int i = 0; i < NSC_; i++){
    // ---- A-frags: leaner input = samp_i[sj] + iap[pj] ----
    bfrag8 afrL[4];
    {
      const float* sp = samp + ((size_t)i * BS_ + (sj < 0 ? 0 : sj)) * HID_;
      #pragma unroll
      for (int kc = 0; kc < 4; kc++){
        int k0 = kc * 32 + kg * 8;
        facc4 s0 = {0,0,0,0}, s1 = {0,0,0,0};
        if (sj >= 0){ s0 = *(const facc4*)(sp + k0); s1 = *(const facc4*)(sp + k0 + 4); }
        usvec4 u0 = ppv[2 * kc], u1 = ppv[2 * kc + 1];
        bfrag8 a;
        a[0] = (short)f2bf(s0.x + bf2f(u0.x)); a[1] = (short)f2bf(s0.y + bf2f(u0.y));
        a[2] = (short)f2bf(s0.z + bf2f(u0.z)); a[3] = (short)f2bf(s0.w + bf2f(u0.w));
        a[4] = (short)f2bf(s1.x + bf2f(u1.x)); a[5] = (short)f2bf(s1.y + bf2f(u1.y));
        a[6] = (short)f2bf(s1.z + bf2f(u1.z)); a[7] = (short)f2bf(s1.w + bf2f(u1.w));
        afrL[kc] = a;
      }
    }
    // imgf A-frags (issued early; consumed in fcs1)
    bfrag8 afrI[4];
    {
      const float* a1 = imgf + ((size_t)i * BM_ + (rv ? row : 0)) * HID_;
      #pragma unroll
      for (int kc = 0; kc < 4; kc++){
        int k0 = kc * 32 + kg * 8;
        facc4 s0 = {0,0,0,0}, s1 = {0,0,0,0};
        if (rv){ s0 = *(const facc4*)(a1 + k0); s1 = *(const facc4*)(a1 + k0 + 4); }
        bfrag8 a;
        a[0]=(short)f2bf(s0.x); a[1]=(short)f2bf(s0.y); a[2]=(short)f2bf(s0.z); a[3]=(short)f2bf(s0.w);
        a[4]=(short)f2bf(s1.x); a[5]=(short)f2bf(s1.y); a[6]=(short)f2bf(s1.z); a[7]=(short)f2bf(s1.w);
        afrI[kc] = a;
      }
    }

    // ---- leaner (two n-halves) ----
    facc4 accL[8];
    #pragma unroll
    for (int a = 0; a < 8; a++) accL[a] = (facc4){0.f, 0.f, 0.f, 0.f};
    #pragma unroll
    for (int h = 0; h < 2; h++){
      stageW(wbuf, (const char*)(lwT + (size_t)i * 16384) + (size_t)h * 64 * 256, 256, tid);
      __syncthreads();
      mfmaHalf(&accL[h * 4], afrL, wbuf, rl, kg);
      __syncthreads();
    }
    // fl = relu(accL + lb) -> act LDS (bf16)
    {
      const float* bias = lb + i * HID_;
      #pragma unroll
      for (int a = 0; a < 8; a++){
        int col = (a >> 2) * 64 + (a & 3) * 16 + rl;
        float bv = bias[col];
        #pragma unroll
        for (int r = 0; r < 4; r++){
          int ar = wv * 16 + kg * 4 + r;
          float v = accL[a][r] + bv; v = v > 0.f ? v : 0.f;
          int byte = ar * 256 + col * 2;
          *(unsigned short*)(actL + (byte ^ ((ar & 7) << 4))) = f2bf(v);
        }
      }
    }
    // ---- fcs1: K-half 0 (imgf) then K-half 1 (fl), each in two n-halves ----
    facc4 accF[8];
    #pragma unroll
    for (int a = 0; a < 8; a++) accF[a] = (facc4){0.f, 0.f, 0.f, 0.f};
    #pragma unroll
    for (int h = 0; h < 2; h++){
      stageW(wbuf, (const char*)(f1T + (size_t)i * 32768) + (size_t)h * 64 * 512, 512, tid);
      __syncthreads();                           // also publishes fl writes
      mfmaHalf(&accF[h * 4], afrI, wbuf, rl, kg);
      __syncthreads();
    }
    bfrag8 afrF[4];
    #pragma unroll
    for (int kc = 0; kc < 4; kc++){
      int byteA = lr * 256 + ((kc * 32 + kg * 8) << 1);
      afrF[kc] = *(const bfrag8*)(actL + (byteA ^ ((lr & 7) << 4)));
    }
    #pragma unroll
    for (int h = 0; h < 2; h++){
      stageW(wbuf, (const char*)(f1T + (size_t)i * 32768) + (size_t)h * 64 * 512 + 256, 512, tid);
      __syncthreads();
      mfmaHalf(&accF[h * 4], afrF, wbuf, rl, kg);
      __syncthreads();
    }
    // fc = accF + b1 (keep f32); also -> act LDS as bf16 for fcs2 A
    {
      const float* bias = f1b + i * HID_;
      #pragma unroll
      for (int a = 0; a < 8; a++){
        int col = (a >> 2) * 64 + (a & 3) * 16 + rl;
        float bv = bias[col];
        #pragma unroll
        for (int r = 0; r < 4; r++){
          int ar = wv * 16 + kg * 4 + r;
          float v = accF[a][r] + bv;
          accF[a][r] = v;
          int byte = ar * 256 + col * 2;
          *(unsigned short*)(actL + (byte ^ ((ar & 7) << 4))) = f2bf(v);
        }
      }
    }
    // ---- fcs2 (two n-halves) ----
    facc4 accT[8];
    #pragma unroll
    for (int a = 0; a < 8; a++) accT[a] = (facc4){0.f, 0.f, 0.f, 0.f};
    bfrag8 afrC[4];
    #pragma unroll
    for (int h = 0; h < 2; h++){
      stageW(wbuf, (const char*)(f2T + (size_t)i * 16384) + (size_t)h * 64 * 256, 256, tid);
      __syncthreads();                           // publishes fc writes (h==0)
      if (h == 0){
        #pragma unroll
        for (int kc = 0; kc < 4; kc++){
          int byteA = lr * 256 + ((kc * 32 + kg * 8) << 1);
          afrC[kc] = *(const bfrag8*)(actL + (byteA ^ ((lr & 7) << 4)));
        }
      }
      mfmaHalf(&accT[h * 4], afrC, wbuf, rl, kg);
      __syncthreads();
    }
    // gate: fuse = relu(fc * sigmoid(accT + b2)) -> act LDS
    {
      const float* bias2 = f2b + i * HID_;
      #pragma unroll
      for (int a = 0; a < 8; a++){
        int col = (a >> 2) * 64 + (a & 3) * 16 + rl;
        float bv2 = bias2[col];
        #pragma unroll
        for (int r = 0; r < 4; r++){
          int ar = wv * 16 + kg * 4 + r;
          float tv = accT[a][r] + bv2;
          float fw = 1.f / (1.f + expf(-tv));
          float u = accF[a][r] * fw;
          u = u > 0.f ? u : 0.f;
          int byte = ar * 256 + col * 2;
          *(unsigned short*)(actL + (byte ^ ((ar & 7) << 4))) = f2bf(u);
        }
      }
    }
    __syncthreads();                             // fuse published
    // ---- cls1 chunk i: accC += fuse @ W1[i*128:(i+1)*128, :] ----
    bfrag8 afrU[4];
    #pragma unroll
    for (int kc = 0; kc < 4; kc++){
      int byteA = lr * 256 + ((kc * 32 + kg * 8) << 1);
      afrU[kc] = *(const bfrag8*)(actL + (byteA ^ ((lr & 7) << 4)));
    }
    #pragma unroll
    for (int h = 0; h < 2; h++){
      stageW(wbuf, (const char*)c1T + (size_t)h * 64 * 1024 + i * 256, 1024, tid);
      __syncthreads();
      mfmaHalf(&accC[h * 4], afrU, wbuf, rl, kg);
      __syncthreads();
    }
  }

  // ---- classifier epilogue: hid = relu(accC + c1b) -> act; W2 dot ----
  #pragma unroll
  for (int a = 0; a < 8; a++){
    int col = (a >> 2) * 64 + (a & 3) * 16 + rl;
    float bv = c1b[col];
    #pragma unroll
    for (int r = 0; r < 4; r++){
      int ar = wv * 16 + kg * 4 + r;
      float v = accC[a][r] + bv; v = v > 0.f ? v : 0.f;
      int byte = ar * 256 + col * 2;
      *(unsigned short*)(actL + (byte ^ ((ar & 7) << 4))) = f2bf(v);
    }
  }
  for (int c = tid; c < 320; c += 256)
    *(bfrag8*)(wbuf + (c << 4)) = *(const bfrag8*)((const char*)c2T + (c << 4));
  __syncthreads();
  {
    int lrd = tid >> 2, n0 = (tid & 3) * 5;
    int orow = blockIdx.x * 64 + lrd;
    if (orow < BM_){
      float accD[5];
      #pragma unroll
      for (int q = 0; q < 5; q++) accD[q] = c2b[n0 + q];
      #pragma unroll
      for (int k8 = 0; k8 < 16; k8++){
        int byteA = lrd * 256 + (k8 << 4);
        bfrag8 hv = *(const bfrag8*)(actL + (byteA ^ ((lrd & 7) << 4)));
        #pragma unroll
        for (int q = 0; q < 5; q++){
          bfrag8 w8 = *(const bfrag8*)(wbuf + (n0 + q) * 256 + (k8 << 4));
          #pragma unroll
          for (int e = 0; e < 8; e++)
            accD[q] += bf2f((unsigned short)hv[e]) * bf2f((unsigned short)w8[e]);
        }
      }
      #pragma unroll
      for (int q = 0; q < 5; q++)
        logits[(size_t)orow * NCLS_ + n0 + q] = accD[q];
    }
  }
}

// ---------------------------------------------------------------------------
extern "C" void kernel_launch(void* const* d_in, const int* in_sizes, int n_in,
                              void* d_out, int out_size, void* d_ws, size_t ws_size,
                              hipStream_t stream){
  const float* samp = (const float*)d_in[1];   // pts_sample_feat (pts_feat_layers is dead)
  const float* img  = (const float*)d_in[2];
  const float* imgf = (const float*)d_in[3];
  const float* lW   = (const float*)d_in[4];
  const float* lb   = (const float*)d_in[5];
  const float* f1W  = (const float*)d_in[6];
  const float* f1b  = (const float*)d_in[7];
  const float* f2W  = (const float*)d_in[8];
  const float* f2b  = (const float*)d_in[9];
  const float* c1W  = (const float*)d_in[10];
  const float* c1b  = (const float*)d_in[11];
  const float* c2W  = (const float*)d_in[12];
  const float* c2b  = (const float*)d_in[13];
  const int* ptsimg = (const int*)d_in[14];
  const int* p2i    = (const int*)d_in[15];
  const int* si     = (const int*)d_in[16];
  const int* ci     = (const int*)d_in[17];

  char* ws = (char*)d_ws;
  int*   win_p = (int*)(ws + 0);                       //   960,000 B
  int*   win_s = (int*)(ws + 960000);                  //   960,000 B
  int*   win_c = (int*)(ws + 1920000);                 //   400,000 B
  unsigned short* iap = (unsigned short*)(ws + 2320128);    // 15,360,000 B
  unsigned short* lwT = (unsigned short*)(ws + 17680384);   // 131,072 B
  unsigned short* f1T = lwT + 65536;                        // 262,144 B
  unsigned short* f2T = f1T + 131072;                       // 131,072 B
  unsigned short* c1T = f2T + 65536;                        // 131,072 B
  unsigned short* c2T = c1T + 65536;                        //   5,120 B

  float* logits = (float*)d_out;
  float* o3d    = (float*)d_out + (size_t)BM_ * NCLS_;

  (void)hipMemsetAsync(ws, 0xFF, 2320000, stream);     // win_* = -1
  k_front<<<5978, 256, 0, stream>>>(img, ptsimg, iap, p2i, si, ci,
                                    win_p, win_s, win_c,
                                    lW, f1W, f2W, c1W, c2W,
                                    lwT, f1T, f2T, c1T, c2T);
  k_o3d  <<<7500, 256, 0, stream>>>(samp, win_s, win_p, iap, o3d);
  k_fused<<<938,  256, 0, stream>>>(samp, iap, win_p, win_s, win_c, p2i, ci,
                                    imgf, lwT, lb, f1T, f1b, f2T, f2b,
                                    c1T, c1b, c2T, c2b, logits);
}